// Round 5
// baseline (8580.405 us; speedup 1.0000x reference)
//
#include <hip/hip_runtime.h>
#include <math.h>

// Dims: B=64, N=1024, M=32, T=25, R=512, SO=512, OD=10
#define TRW 57
#define TRN (TRW * 64)   // floats per n in trace, layout [n][col][b]
#define NBLK 512

struct Params {
  const float *x, *sas, *st;
  const float *ie_w1, *ie_b1, *ie_g1, *ie_bn1;
  const float *ie_w2, *ie_b2, *ie_g2, *ie_bn2;
  const float *ie_w3, *ie_b3;
  const float *kv_w, *kv_b, *kv_g, *kv_bn;
  const float *ip_w, *ip_b, *op_w, *op_b;
  const float *syn_w, *syn_b, *syn_g, *syn_bn;
  const float *nlm_w1, *nlm_b1, *nlm_w2, *nlm_b2;
  const float *decay_o;
  const float *op_w1, *op_b1, *op_g1, *op_bn1;
  const float *op_w2, *op_b2, *op_g2, *op_bn2;
  const float *op_w3, *op_b3;
  const int *il, *ir;
  float *out;
  unsigned *bar;
  float *attn, *act, *aO, *bO, *ns, *w1t, *w2t, *part, *trace;
  float *eb1, *eb2, *enc, *kv, *vv;
};

// software grid barrier: all NBLK blocks co-resident (LDS 45KB -> 3/CU,
// launch_bounds(256,2) -> VGPR<=256 -> 2/CU; grid = 2*256 exactly).
__device__ __forceinline__ void gsync(unsigned* cnt, unsigned& tgt) {
  __syncthreads();
  if (threadIdx.x == 0) {
    tgt += NBLK;
    __threadfence();                       // release (L2 writeback)
    atomicAdd(cnt, 1u);
    while (atomicAdd(cnt, 0u) < tgt) __builtin_amdgcn_s_sleep(2);
    __threadfence();                       // acquire (invalidate stale)
  }
  __syncthreads();
}

__device__ __forceinline__ float wave_sum(float v) {
  #pragma unroll
  for (int off = 32; off; off >>= 1) v += __shfl_xor(v, off, 64);
  return v;
}

__device__ __forceinline__ float2 block_sum2_256(float a, float b, float2* sh) {
  a = wave_sum(a); b = wave_sum(b);
  int w = threadIdx.x >> 6, l = threadIdx.x & 63;
  if (l == 0) sh[w] = make_float2(a, b);
  __syncthreads();
  float2 r = make_float2(0.f, 0.f);
  #pragma unroll
  for (int i = 0; i < 4; i++) { r.x += sh[i].x; r.y += sh[i].y; }
  __syncthreads();
  return r;
}

__device__ __forceinline__ float sigmoidf(float x) {
  return 1.f / (1.f + expf(-x));
}

// output-parallel GEMV: out[64][O] = A[64][K] @ W[O][K]^T + bias
// 8 blocks per b (b = g>>3), 4 waves/block, each wave does groups of 4 outputs
__device__ void gemv4(int g, int tid, const float* __restrict__ A,
                      const float* __restrict__ W, const float* __restrict__ bias,
                      float* __restrict__ out, int K, int O, float* aL) {
  int b = g >> 3, w = tid >> 6, l = tid & 63;
  for (int k = tid; k < K; k += 256) aL[k] = A[b * K + k];
  __syncthreads();
  int wb = (g & 7) * 4 + w;
  int ngrp = O >> 2;
  for (int gi = wb; gi < ngrp; gi += 32) {
    int o0 = gi * 4;
    float s0 = 0.f, s1 = 0.f, s2 = 0.f, s3 = 0.f;
    for (int ki = l; ki < K; ki += 64) {
      float av = aL[ki];
      s0 = fmaf(av, W[(o0 + 0) * K + ki], s0);
      s1 = fmaf(av, W[(o0 + 1) * K + ki], s1);
      s2 = fmaf(av, W[(o0 + 2) * K + ki], s2);
      s3 = fmaf(av, W[(o0 + 3) * K + ki], s3);
    }
    s0 = wave_sum(s0); s1 = wave_sum(s1); s2 = wave_sum(s2); s3 = wave_sum(s3);
    if (l == 0) {
      out[b * O + o0 + 0] = s0 + bias[o0 + 0];
      out[b * O + o0 + 1] = s1 + bias[o0 + 1];
      out[b * O + o0 + 2] = s2 + bias[o0 + 2];
      out[b * O + o0 + 3] = s3 + bias[o0 + 3];
    }
  }
  __syncthreads();
}

__device__ void ln_ip(int tid, float* buf, const float* ga, const float* be,
                      int V, bool relu, float2* shred) {
  float x0 = 0.f, x1 = 0.f, v0 = 0.f, v1 = 0.f;
  if (V == 512) {
    x0 = buf[tid]; x1 = buf[tid + 256];
    v0 = x0 + x1; v1 = x0 * x0 + x1 * x1;
  } else if (tid < V) {
    x0 = buf[tid]; v0 = x0; v1 = x0 * x0;
  }
  float2 s = block_sum2_256(v0, v1, shred);
  float mu = s.x / V, var = s.y / V - mu * mu;
  float is = rsqrtf(var + 1e-5f);
  if (V == 512) {
    float y0 = (x0 - mu) * is * ga[tid] + be[tid];
    float y1 = (x1 - mu) * is * ga[tid + 256] + be[tid + 256];
    buf[tid] = relu ? fmaxf(y0, 0.f) : y0;
    buf[tid + 256] = relu ? fmaxf(y1, 0.f) : y1;
  } else if (tid < V) {
    float y = (x0 - mu) * is * ga[tid] + be[tid];
    buf[tid] = relu ? fmaxf(y, 0.f) : y;
  }
}

// op head for batch row b at step t; 256 threads
__device__ void op_body(int b, int t, const Params& P, float* sm, float2* shred) {
  float* so = sm;            // 512
  float* p1s = sm + 512;     // 256
  float* qred = sm + 768;    // 256
  float* p2s = sm + 1024;    // 64
  float* preds = sm + 1088;  // 10
  int tid = threadIdx.x;
  #pragma unroll
  for (int r = 0; r < 2; r++) {
    int o = r * 256 + tid;
    float rr = expf(-fminf(fmaxf(P.decay_o[o], 0.f), 15.f));
    float pp = P.act[b * 1024 + P.il[o]] * P.act[b * 1024 + P.ir[o]];
    float a = rr * P.aO[b * 512 + o] + pp;
    float bbv = rr * P.bO[b * 512 + o] + 1.f;
    P.aO[b * 512 + o] = a;
    P.bO[b * 512 + o] = bbv;
    so[o] = a * rsqrtf(bbv + 1e-8f);
  }
  __syncthreads();
  float p = P.op_b1[tid];
  #pragma unroll 8
  for (int k = 0; k < 512; k++) p += so[k] * P.w1t[k * 256 + tid];
  float2 s = block_sum2_256(p, p * p, shred);
  {
    float mu = s.x * (1.f / 256.f), var = s.y * (1.f / 256.f) - mu * mu;
    p1s[tid] = fmaxf((p - mu) * rsqrtf(var + 1e-5f) * P.op_g1[tid] + P.op_bn1[tid], 0.f);
  }
  __syncthreads();
  {
    int o = tid & 63, tg = tid >> 6;
    float q = 0.f;
    #pragma unroll 4
    for (int j = 0; j < 64; j++) {
      int k = tg * 64 + j;
      q += p1s[k] * P.w2t[k * 64 + o];
    }
    qred[tid] = q;
  }
  __syncthreads();
  if (tid < 64) {
    float p2 = qred[tid] + qred[tid + 64] + qred[tid + 128] + qred[tid + 192] + P.op_b2[tid];
    float sa = wave_sum(p2), sb = wave_sum(p2 * p2);
    float mu = sa * (1.f / 64.f), var = sb * (1.f / 64.f) - mu * mu;
    float y = (p2 - mu) * rsqrtf(var + 1e-5f) * P.op_g2[tid] + P.op_bn2[tid];
    p2s[tid] = fmaxf(y, 0.f);
  }
  __syncthreads();
  if (tid < 160) {
    int o = tid >> 4, j = tid & 15;
    const float* w3r = P.op_w3 + o * 64 + j * 4;
    const float* pp2 = p2s + j * 4;
    float sv = w3r[0] * pp2[0] + w3r[1] * pp2[1] + w3r[2] * pp2[2] + w3r[3] * pp2[3];
    #pragma unroll
    for (int off = 8; off; off >>= 1) sv += __shfl_xor(sv, off, 64);
    if (j == 0) {
      float pr = sv + P.op_b3[o];
      preds[o] = pr;
      P.out[b * 250 + o * 25 + t] = pr;
    }
  }
  __syncthreads();
  if (tid == 0) {
    float mx = preds[0];
    #pragma unroll
    for (int k = 1; k < 10; k++) mx = fmaxf(mx, preds[k]);
    float sum = 0.f, e[10];
    #pragma unroll
    for (int k = 0; k < 10; k++) { e[k] = expf(preds[k] - mx); sum += e[k]; }
    float ent = 0.f;
    #pragma unroll
    for (int k = 0; k < 10; k++) {
      float pr = e[k] / sum;
      ent -= pr * logf(pr + 1e-10f);
    }
    ent *= (1.f / 2.302585093f);
    P.out[16000 + b * 50 + t] = ent;
    P.out[16000 + b * 50 + 25 + t] = 1.f - ent;
  }
  __syncthreads();
}

__global__ __launch_bounds__(256, 2) void k_main(Params P) {
  int g = blockIdx.x, tid = threadIdx.x;
  unsigned bar_tgt = 0;
  __shared__ float smem[11264];     // 44 KB phase-shared scratch
  __shared__ float2 shred[16];

  // ================= phase 0: setup =================
  {
    int gt = g * 256 + tid;  // 0..131071
    #pragma unroll
    for (int r = 0; r < 16; r++) {  // trace cols 0..31
      int i = r * 131072 + gt;      // < 2097152
      int n = i >> 11, rem = i & 2047, j = rem >> 6;
      P.trace[n * TRN + rem] = P.st[n * 32 + j];
    }
    if (gt < 65536) P.act[gt] = P.sas[gt & 1023];
    if (gt < 32768) {
      int o = gt & 511;
      P.aO[gt] = P.sas[P.il[o]] * P.sas[P.ir[o]];
      P.bO[gt] = 1.f;
    }
    { int o = gt & 255, k = gt >> 8; P.w1t[gt] = P.op_w1[o * 512 + k]; }
    if (gt < 16384) { int o = gt & 63, k = gt >> 6; P.w2t[gt] = P.op_w2[o * 256 + k]; }
  }
  gsync(P.bar, bar_tgt);

  // ================= encoder =================
  gemv4(g, tid, P.x, P.ie_w1, P.ie_b1, P.eb1, 784, 128, smem);
  gsync(P.bar, bar_tgt);
  if (g < 64) ln_ip(tid, P.eb1 + g * 128, P.ie_g1, P.ie_bn1, 128, true, shred);
  gsync(P.bar, bar_tgt);
  gemv4(g, tid, P.eb1, P.ie_w2, P.ie_b2, P.eb2, 128, 64, smem);
  gsync(P.bar, bar_tgt);
  if (g < 64) ln_ip(tid, P.eb2 + g * 64, P.ie_g2, P.ie_bn2, 64, true, shred);
  gsync(P.bar, bar_tgt);
  gemv4(g, tid, P.eb2, P.ie_w3, P.ie_b3, P.enc, 64, 512, smem);
  gsync(P.bar, bar_tgt);
  gemv4(g, tid, P.enc, P.kv_w, P.kv_b, P.kv, 512, 512, smem);
  gsync(P.bar, bar_tgt);
  if (g < 64) ln_ip(tid, P.kv + g * 512, P.kv_g, P.kv_bn, 512, false, shred);
  gsync(P.bar, bar_tgt);
  gemv4(g, tid, P.kv, P.ip_w + 1024 * 512, P.ip_b + 1024, P.vv, 512, 512, smem);
  gsync(P.bar, bar_tgt);
  gemv4(g, tid, P.vv, P.op_w, P.op_b, P.attn, 512, 512, smem);
  gsync(P.bar, bar_tgt);

  // ================= 25 steps =================
  for (int t = 0; t < 25; t++) {
    // ---- phase A: syn GEMM, 512 tiles (32 ct x 16 kc), K-chunk 96 ----
    {
      float* pre_t = smem;           // 32*68
      float* w_lds = smem + 2176;    // 32*68
      int ct = g & 31, kc = g >> 5;
      int tb = tid >> 4, tc = tid & 15;
      int b0 = tb * 4, c0 = tc * 4;
      float acc[4][4];
      #pragma unroll
      for (int i = 0; i < 4; i++)
        #pragma unroll
        for (int j = 0; j < 4; j++) acc[i][j] = 0.f;
      for (int kt = 0; kt < 96; kt += 32) {
        int k0 = kc * 96 + kt;
        #pragma unroll
        for (int r = 0; r < 8; r++) {
          int idx = r * 256 + tid;
          int kk = idx & 31, bb = idx >> 5;
          int kg = k0 + kk;
          float pv = (kg < 512) ? P.attn[bb * 512 + kg] : P.act[bb * 1024 + (kg - 512)];
          pre_t[kk * 68 + bb] = pv;
          w_lds[kk * 68 + bb] = P.syn_w[(ct * 64 + bb) * 1536 + kg];
        }
        __syncthreads();
        #pragma unroll 8
        for (int kk = 0; kk < 32; kk++) {
          float4 av = *(const float4*)(pre_t + kk * 68 + b0);
          float4 wv = *(const float4*)(w_lds + kk * 68 + c0);
          float a[4] = {av.x, av.y, av.z, av.w};
          float w[4] = {wv.x, wv.y, wv.z, wv.w};
          #pragma unroll
          for (int i = 0; i < 4; i++)
            #pragma unroll
            for (int j = 0; j < 4; j++) acc[i][j] += a[i] * w[j];
        }
        __syncthreads();
      }
      float* pb = P.part + kc * 131072;
      #pragma unroll
      for (int i = 0; i < 4; i++) {
        float4 st4 = make_float4(acc[i][0], acc[i][1], acc[i][2], acc[i][3]);
        *(float4*)(pb + (b0 + i) * 2048 + ct * 64 + c0) = st4;
      }
    }
    gsync(P.bar, bar_tgt);

    // ---- phase B: syn_ln (blocks 0..63) + op(t-1) (blocks 64..127) ----
    if (g < 64) {
      float val[4];
      float s0 = 0.f, s1 = 0.f;
      #pragma unroll
      for (int j = 0; j < 4; j++) {
        int n = tid + j * 256;
        float a = P.syn_b[n], gg = P.syn_b[n + 1024];
        #pragma unroll
        for (int kc = 0; kc < 16; kc++) {
          const float* pb = P.part + kc * 131072 + g * 2048;
          a += pb[n];
          gg += pb[n + 1024];
        }
        float v = a * sigmoidf(gg);
        val[j] = v; s0 += v; s1 += v * v;
      }
      float2 s = block_sum2_256(s0, s1, shred);
      float mu = s.x * (1.f / 1024.f), var = s.y * (1.f / 1024.f) - mu * mu;
      float is = rsqrtf(var + 1e-5f);
      #pragma unroll
      for (int j = 0; j < 4; j++) {
        int n = tid + j * 256;
        P.ns[g * 1024 + n] = (val[j] - mu) * is * P.syn_g[n] + P.syn_bn[n];
      }
    } else if (g < 128) {
      if (t > 0) op_body(g - 64, t - 1, P, smem, shred);
    }
    gsync(P.bar, bar_tgt);

    // ---- phase C: NLM, 2 n per block ----
    {
      float* At = smem;              // 32*68
      float* w1s = smem + 2176;      // 8192
      float* b1s = smem + 10368;     // 256
      float* w2s = smem + 10624;     // 128
      int tb = tid >> 5, tjj = tid & 31;
      for (int q = 0; q < 2; q++) {
        int n = g * 2 + q;
        const float4* tw4 = (const float4*)(P.trace + n * TRN + (t + 1) * 64);
        #pragma unroll
        for (int r = 0; r < 2; r++) {
          int idx = r * 256 + tid;
          if (idx < 496) {
            float4 f4 = tw4[idx];
            int fo = idx * 4, m = fo >> 6, bb = fo & 63;
            *(float4*)(At + m * 68 + bb) = f4;
          }
        }
        if (tid < 64) {
          float v = P.ns[tid * 1024 + n];
          At[31 * 68 + tid] = v;
          P.trace[n * TRN + (32 + t) * 64 + tid] = v;
        }
        const float4* w1n = (const float4*)(P.nlm_w1 + n * 8192);
        float4* w1s4 = (float4*)w1s;
        #pragma unroll
        for (int r = 0; r < 8; r++) w1s4[r * 256 + tid] = w1n[r * 256 + tid];
        b1s[tid] = P.nlm_b1[n * 256 + tid];
        if (tid < 128) w2s[tid] = P.nlm_w2[n * 128 + tid];
        __syncthreads();

        float h[8][8];
        #pragma unroll
        for (int jj = 0; jj < 8; jj++) {
          float bv = b1s[tjj + 32 * jj];
          #pragma unroll
          for (int i = 0; i < 8; i++) h[i][jj] = bv;
        }
        for (int m = 0; m < 32; m++) {
          float4 a0 = *(const float4*)(At + m * 68 + tb * 8);
          float4 a1 = *(const float4*)(At + m * 68 + tb * 8 + 4);
          float a[8] = {a0.x, a0.y, a0.z, a0.w, a1.x, a1.y, a1.z, a1.w};
          float wv[8];
          #pragma unroll
          for (int jj = 0; jj < 8; jj++) wv[jj] = w1s[m * 256 + tjj + 32 * jj];
          #pragma unroll
          for (int i = 0; i < 8; i++)
            #pragma unroll
            for (int jj = 0; jj < 8; jj++) h[i][jj] += a[i] * wv[jj];
        }
        float b2n = P.nlm_b2[n];
        #pragma unroll
        for (int i = 0; i < 8; i++) {
          float p = 0.f;
          #pragma unroll
          for (int jj = 0; jj < 4; jj++) {
            float hh = h[i][jj] * sigmoidf(h[i][jj + 4]);
            p += hh * w2s[tjj + 32 * jj];
          }
          #pragma unroll
          for (int off = 16; off > 0; off >>= 1) p += __shfl_xor(p, off, 64);
          if (tjj == 0) P.act[(tb * 8 + i) * 1024 + n] = p + b2n;
        }
        __syncthreads();
      }
    }
    gsync(P.bar, bar_tgt);
  }

  // ---- tail: op head for t=24 ----
  if (g < 64) op_body(g, 24, P, smem, shred);
}

extern "C" void kernel_launch(void* const* d_in, const int* in_sizes, int n_in,
                              void* d_out, int out_size, void* d_ws, size_t ws_size,
                              hipStream_t stream) {
  Params P;
  P.x       = (const float*)d_in[0];
  P.sas     = (const float*)d_in[1];
  P.st      = (const float*)d_in[2];
  P.ie_w1   = (const float*)d_in[3];
  P.ie_b1   = (const float*)d_in[4];
  P.ie_g1   = (const float*)d_in[5];
  P.ie_bn1  = (const float*)d_in[6];
  P.ie_w2   = (const float*)d_in[7];
  P.ie_b2   = (const float*)d_in[8];
  P.ie_g2   = (const float*)d_in[9];
  P.ie_bn2  = (const float*)d_in[10];
  P.ie_w3   = (const float*)d_in[11];
  P.ie_b3   = (const float*)d_in[12];
  P.kv_w    = (const float*)d_in[13];
  P.kv_b    = (const float*)d_in[14];
  P.kv_g    = (const float*)d_in[15];
  P.kv_bn   = (const float*)d_in[16];
  P.ip_w    = (const float*)d_in[19];
  P.ip_b    = (const float*)d_in[20];
  P.op_w    = (const float*)d_in[21];
  P.op_b    = (const float*)d_in[22];
  P.syn_w   = (const float*)d_in[23];
  P.syn_b   = (const float*)d_in[24];
  P.syn_g   = (const float*)d_in[25];
  P.syn_bn  = (const float*)d_in[26];
  P.nlm_w1  = (const float*)d_in[27];
  P.nlm_b1  = (const float*)d_in[28];
  P.nlm_w2  = (const float*)d_in[29];
  P.nlm_b2  = (const float*)d_in[30];
  P.decay_o = (const float*)d_in[32];
  P.op_w1   = (const float*)d_in[33];
  P.op_b1   = (const float*)d_in[34];
  P.op_g1   = (const float*)d_in[35];
  P.op_bn1  = (const float*)d_in[36];
  P.op_w2   = (const float*)d_in[37];
  P.op_b2   = (const float*)d_in[38];
  P.op_g2   = (const float*)d_in[39];
  P.op_bn2  = (const float*)d_in[40];
  P.op_w3   = (const float*)d_in[41];
  P.op_b3   = (const float*)d_in[42];
  P.il      = (const int*)d_in[43];
  P.ir      = (const int*)d_in[44];
  P.out     = (float*)d_out;

  float* ws = (float*)d_ws;
  P.bar   = (unsigned*)ws;         // 64 floats reserved (one cacheline used)
  P.attn  = ws + 64;               // 32768
  P.act   = P.attn + 32768;        // 65536
  P.aO    = P.act + 65536;         // 32768
  P.bO    = P.aO + 32768;          // 32768
  P.ns    = P.bO + 32768;          // 65536
  P.w1t   = P.ns + 65536;          // 131072
  P.w2t   = P.w1t + 131072;        // 16384
  P.part  = P.w2t + 16384;         // 16*64*2048 = 2097152
  P.trace = P.part + 2097152;      // 1024*3648 = 3735552
  P.eb1   = P.trace + 3735552;     // 8192
  P.eb2   = P.eb1 + 8192;          // 4096
  P.enc   = P.eb2 + 4096;          // 32768
  P.kv    = P.enc + 32768;         // 32768
  P.vv    = P.kv + 32768;          // 32768

  hipMemsetAsync(P.bar, 0, 256, stream);
  k_main<<<NBLK, 256, 0, stream>>>(P);
}

// Round 6
// 7211.835 us; speedup vs baseline: 1.1898x; 1.1898x over previous
//
#include <hip/hip_runtime.h>
#include <math.h>

// Dims: B=64, N=1024, M=32, T=25, R=512, SO=512, OD=10
#define TRW 57
#define TRN (TRW * 64)   // floats per n in trace, layout [n][col][b]
#define NBLK 512

struct Params {
  const float *x, *sas, *st;
  const float *ie_w1, *ie_b1, *ie_g1, *ie_bn1;
  const float *ie_w2, *ie_b2, *ie_g2, *ie_bn2;
  const float *ie_w3, *ie_b3;
  const float *kv_w, *kv_b, *kv_g, *kv_bn;
  const float *ip_w, *ip_b, *op_w, *op_b;
  const float *syn_w, *syn_b, *syn_g, *syn_bn;
  const float *nlm_w1, *nlm_b1, *nlm_w2, *nlm_b2;
  const float *decay_o;
  const float *op_w1, *op_b1, *op_g1, *op_bn1;
  const float *op_w2, *op_b2, *op_g2, *op_bn2;
  const float *op_w3, *op_b3;
  const int *il, *ir;
  float *out;
  unsigned *bar;
  float *attn, *act, *aO, *bO, *ns, *w1t, *w2t, *part, *trace;
  float *eb1, *eb2, *enc, *kv, *vv;
};

// Software grid barrier. All NBLK blocks co-resident (LDS 45KB -> 3/CU,
// launch_bounds(256,2) -> 2/CU by VGPR; grid = 2*256 exactly).
// Arrival: 1 atomicAdd per block, spread over 8 cachelines (g&7).
// Spin: agent-scope LOADS only (no RMW ping-pong). Monotone epoch.
__device__ __forceinline__ void gsync(unsigned* bar, unsigned& epoch) {
  __syncthreads();
  if (threadIdx.x == 0) {
    epoch += 1;
    unsigned target = epoch * (NBLK / 8);   // 64 arrivals per counter per epoch
    __threadfence();                        // release: publish prior writes
    __hip_atomic_fetch_add(&bar[(blockIdx.x & 7) * 32], 1u,
                           __ATOMIC_RELAXED, __HIP_MEMORY_SCOPE_AGENT);
    for (;;) {
      unsigned ok = 0;
      #pragma unroll
      for (int i = 0; i < 8; i++)
        ok += (__hip_atomic_load(&bar[i * 32], __ATOMIC_RELAXED,
                                 __HIP_MEMORY_SCOPE_AGENT) >= target) ? 1u : 0u;
      if (ok == 8) break;
      __builtin_amdgcn_s_sleep(1);
    }
    __threadfence();                        // acquire: invalidate stale
  }
  __syncthreads();
}

__device__ __forceinline__ float wave_sum(float v) {
  #pragma unroll
  for (int off = 32; off; off >>= 1) v += __shfl_xor(v, off, 64);
  return v;
}

__device__ __forceinline__ float2 block_sum2_256(float a, float b, float2* sh) {
  a = wave_sum(a); b = wave_sum(b);
  int w = threadIdx.x >> 6, l = threadIdx.x & 63;
  if (l == 0) sh[w] = make_float2(a, b);
  __syncthreads();
  float2 r = make_float2(0.f, 0.f);
  #pragma unroll
  for (int i = 0; i < 4; i++) { r.x += sh[i].x; r.y += sh[i].y; }
  __syncthreads();
  return r;
}

__device__ __forceinline__ float sigmoidf(float x) {
  return 1.f / (1.f + expf(-x));
}

// output-parallel GEMV: out[64][O] = A[64][K] @ W[O][K]^T + bias
// 8 blocks per b (b = g>>3), 4 waves/block, each wave does groups of 4 outputs
__device__ void gemv4(int g, int tid, const float* __restrict__ A,
                      const float* __restrict__ W, const float* __restrict__ bias,
                      float* __restrict__ out, int K, int O, float* aL) {
  int b = g >> 3, w = tid >> 6, l = tid & 63;
  for (int k = tid; k < K; k += 256) aL[k] = A[b * K + k];
  __syncthreads();
  int wb = (g & 7) * 4 + w;
  int ngrp = O >> 2;
  for (int gi = wb; gi < ngrp; gi += 32) {
    int o0 = gi * 4;
    float s0 = 0.f, s1 = 0.f, s2 = 0.f, s3 = 0.f;
    for (int ki = l; ki < K; ki += 64) {
      float av = aL[ki];
      s0 = fmaf(av, W[(o0 + 0) * K + ki], s0);
      s1 = fmaf(av, W[(o0 + 1) * K + ki], s1);
      s2 = fmaf(av, W[(o0 + 2) * K + ki], s2);
      s3 = fmaf(av, W[(o0 + 3) * K + ki], s3);
    }
    s0 = wave_sum(s0); s1 = wave_sum(s1); s2 = wave_sum(s2); s3 = wave_sum(s3);
    if (l == 0) {
      out[b * O + o0 + 0] = s0 + bias[o0 + 0];
      out[b * O + o0 + 1] = s1 + bias[o0 + 1];
      out[b * O + o0 + 2] = s2 + bias[o0 + 2];
      out[b * O + o0 + 3] = s3 + bias[o0 + 3];
    }
  }
  __syncthreads();
}

__device__ void ln_ip(int tid, float* buf, const float* ga, const float* be,
                      int V, bool relu, float2* shred) {
  float x0 = 0.f, x1 = 0.f, v0 = 0.f, v1 = 0.f;
  if (V == 512) {
    x0 = buf[tid]; x1 = buf[tid + 256];
    v0 = x0 + x1; v1 = x0 * x0 + x1 * x1;
  } else if (tid < V) {
    x0 = buf[tid]; v0 = x0; v1 = x0 * x0;
  }
  float2 s = block_sum2_256(v0, v1, shred);
  float mu = s.x / V, var = s.y / V - mu * mu;
  float is = rsqrtf(var + 1e-5f);
  if (V == 512) {
    float y0 = (x0 - mu) * is * ga[tid] + be[tid];
    float y1 = (x1 - mu) * is * ga[tid + 256] + be[tid + 256];
    buf[tid] = relu ? fmaxf(y0, 0.f) : y0;
    buf[tid + 256] = relu ? fmaxf(y1, 0.f) : y1;
  } else if (tid < V) {
    float y = (x0 - mu) * is * ga[tid] + be[tid];
    buf[tid] = relu ? fmaxf(y, 0.f) : y;
  }
}

// op head for batch row b at step t; 256 threads
__device__ void op_body(int b, int t, const Params& P, float* sm, float2* shred) {
  float* so = sm;            // 512
  float* p1s = sm + 512;     // 256
  float* qred = sm + 768;    // 256
  float* p2s = sm + 1024;    // 64
  float* preds = sm + 1088;  // 10
  int tid = threadIdx.x;
  #pragma unroll
  for (int r = 0; r < 2; r++) {
    int o = r * 256 + tid;
    float rr = expf(-fminf(fmaxf(P.decay_o[o], 0.f), 15.f));
    float pp = P.act[b * 1024 + P.il[o]] * P.act[b * 1024 + P.ir[o]];
    float a = rr * P.aO[b * 512 + o] + pp;
    float bbv = rr * P.bO[b * 512 + o] + 1.f;
    P.aO[b * 512 + o] = a;
    P.bO[b * 512 + o] = bbv;
    so[o] = a * rsqrtf(bbv + 1e-8f);
  }
  __syncthreads();
  float p = P.op_b1[tid];
  #pragma unroll 8
  for (int k = 0; k < 512; k++) p += so[k] * P.w1t[k * 256 + tid];
  float2 s = block_sum2_256(p, p * p, shred);
  {
    float mu = s.x * (1.f / 256.f), var = s.y * (1.f / 256.f) - mu * mu;
    p1s[tid] = fmaxf((p - mu) * rsqrtf(var + 1e-5f) * P.op_g1[tid] + P.op_bn1[tid], 0.f);
  }
  __syncthreads();
  {
    int o = tid & 63, tg = tid >> 6;
    float q = 0.f;
    #pragma unroll 4
    for (int j = 0; j < 64; j++) {
      int k = tg * 64 + j;
      q += p1s[k] * P.w2t[k * 64 + o];
    }
    qred[tid] = q;
  }
  __syncthreads();
  if (tid < 64) {
    float p2 = qred[tid] + qred[tid + 64] + qred[tid + 128] + qred[tid + 192] + P.op_b2[tid];
    float sa = wave_sum(p2), sb = wave_sum(p2 * p2);
    float mu = sa * (1.f / 64.f), var = sb * (1.f / 64.f) - mu * mu;
    float y = (p2 - mu) * rsqrtf(var + 1e-5f) * P.op_g2[tid] + P.op_bn2[tid];
    p2s[tid] = fmaxf(y, 0.f);
  }
  __syncthreads();
  if (tid < 160) {
    int o = tid >> 4, j = tid & 15;
    const float* w3r = P.op_w3 + o * 64 + j * 4;
    const float* pp2 = p2s + j * 4;
    float sv = w3r[0] * pp2[0] + w3r[1] * pp2[1] + w3r[2] * pp2[2] + w3r[3] * pp2[3];
    #pragma unroll
    for (int off = 8; off; off >>= 1) sv += __shfl_xor(sv, off, 64);
    if (j == 0) {
      float pr = sv + P.op_b3[o];
      preds[o] = pr;
      P.out[b * 250 + o * 25 + t] = pr;
    }
  }
  __syncthreads();
  if (tid == 0) {
    float mx = preds[0];
    #pragma unroll
    for (int k = 1; k < 10; k++) mx = fmaxf(mx, preds[k]);
    float sum = 0.f, e[10];
    #pragma unroll
    for (int k = 0; k < 10; k++) { e[k] = expf(preds[k] - mx); sum += e[k]; }
    float ent = 0.f;
    #pragma unroll
    for (int k = 0; k < 10; k++) {
      float pr = e[k] / sum;
      ent -= pr * logf(pr + 1e-10f);
    }
    ent *= (1.f / 2.302585093f);
    P.out[16000 + b * 50 + t] = ent;
    P.out[16000 + b * 50 + 25 + t] = 1.f - ent;
  }
  __syncthreads();
}

__global__ __launch_bounds__(256, 2) void k_main(Params P) {
  int g = blockIdx.x, tid = threadIdx.x;
  unsigned epoch = 0;
  __shared__ float smem[11264];     // 44 KB phase-shared scratch
  __shared__ float2 shred[16];

  // ================= phase 0: setup =================
  {
    int gt = g * 256 + tid;  // 0..131071
    #pragma unroll
    for (int r = 0; r < 16; r++) {  // trace cols 0..31
      int i = r * 131072 + gt;      // < 2097152
      int n = i >> 11, rem = i & 2047, j = rem >> 6;
      P.trace[n * TRN + rem] = P.st[n * 32 + j];
    }
    if (gt < 65536) P.act[gt] = P.sas[gt & 1023];
    if (gt < 32768) {
      int o = gt & 511;
      P.aO[gt] = P.sas[P.il[o]] * P.sas[P.ir[o]];
      P.bO[gt] = 1.f;
    }
    { int o = gt & 255, k = gt >> 8; P.w1t[gt] = P.op_w1[o * 512 + k]; }
    if (gt < 16384) { int o = gt & 63, k = gt >> 6; P.w2t[gt] = P.op_w2[o * 256 + k]; }
  }
  gsync(P.bar, epoch);

  // ================= encoder =================
  gemv4(g, tid, P.x, P.ie_w1, P.ie_b1, P.eb1, 784, 128, smem);
  gsync(P.bar, epoch);
  if (g < 64) ln_ip(tid, P.eb1 + g * 128, P.ie_g1, P.ie_bn1, 128, true, shred);
  gsync(P.bar, epoch);
  gemv4(g, tid, P.eb1, P.ie_w2, P.ie_b2, P.eb2, 128, 64, smem);
  gsync(P.bar, epoch);
  if (g < 64) ln_ip(tid, P.eb2 + g * 64, P.ie_g2, P.ie_bn2, 64, true, shred);
  gsync(P.bar, epoch);
  gemv4(g, tid, P.eb2, P.ie_w3, P.ie_b3, P.enc, 64, 512, smem);
  gsync(P.bar, epoch);
  gemv4(g, tid, P.enc, P.kv_w, P.kv_b, P.kv, 512, 512, smem);
  gsync(P.bar, epoch);
  if (g < 64) ln_ip(tid, P.kv + g * 512, P.kv_g, P.kv_bn, 512, false, shred);
  gsync(P.bar, epoch);
  gemv4(g, tid, P.kv, P.ip_w + 1024 * 512, P.ip_b + 1024, P.vv, 512, 512, smem);
  gsync(P.bar, epoch);
  gemv4(g, tid, P.vv, P.op_w, P.op_b, P.attn, 512, 512, smem);
  gsync(P.bar, epoch);

  // ================= 25 steps =================
  for (int t = 0; t < 25; t++) {
    // ---- phase A: syn GEMM, 512 tiles (32 ct x 16 kc), K-chunk 96 ----
    {
      float* pre_t = smem;           // 32*68
      float* w_lds = smem + 2176;    // 32*68
      int ct = g & 31, kc = g >> 5;
      int tb = tid >> 4, tc = tid & 15;
      int b0 = tb * 4, c0 = tc * 4;
      float acc[4][4];
      #pragma unroll
      for (int i = 0; i < 4; i++)
        #pragma unroll
        for (int j = 0; j < 4; j++) acc[i][j] = 0.f;
      for (int kt = 0; kt < 96; kt += 32) {
        int k0 = kc * 96 + kt;
        #pragma unroll
        for (int r = 0; r < 8; r++) {
          int idx = r * 256 + tid;
          int kk = idx & 31, bb = idx >> 5;
          int kg = k0 + kk;
          float pv = (kg < 512) ? P.attn[bb * 512 + kg] : P.act[bb * 1024 + (kg - 512)];
          pre_t[kk * 68 + bb] = pv;
          w_lds[kk * 68 + bb] = P.syn_w[(ct * 64 + bb) * 1536 + kg];
        }
        __syncthreads();
        #pragma unroll 8
        for (int kk = 0; kk < 32; kk++) {
          float4 av = *(const float4*)(pre_t + kk * 68 + b0);
          float4 wv = *(const float4*)(w_lds + kk * 68 + c0);
          float a[4] = {av.x, av.y, av.z, av.w};
          float w[4] = {wv.x, wv.y, wv.z, wv.w};
          #pragma unroll
          for (int i = 0; i < 4; i++)
            #pragma unroll
            for (int j = 0; j < 4; j++) acc[i][j] += a[i] * w[j];
        }
        __syncthreads();
      }
      float* pb = P.part + kc * 131072;
      #pragma unroll
      for (int i = 0; i < 4; i++) {
        float4 st4 = make_float4(acc[i][0], acc[i][1], acc[i][2], acc[i][3]);
        *(float4*)(pb + (b0 + i) * 2048 + ct * 64 + c0) = st4;
      }
    }
    gsync(P.bar, epoch);

    // ---- phase B: syn_ln (blocks 0..63) + op(t-1) (blocks 64..127) ----
    if (g < 64) {
      float val[4];
      float s0 = 0.f, s1 = 0.f;
      #pragma unroll
      for (int j = 0; j < 4; j++) {
        int n = tid + j * 256;
        float a = P.syn_b[n], gg = P.syn_b[n + 1024];
        #pragma unroll
        for (int kc = 0; kc < 16; kc++) {
          const float* pb = P.part + kc * 131072 + g * 2048;
          a += pb[n];
          gg += pb[n + 1024];
        }
        float v = a * sigmoidf(gg);
        val[j] = v; s0 += v; s1 += v * v;
      }
      float2 s = block_sum2_256(s0, s1, shred);
      float mu = s.x * (1.f / 1024.f), var = s.y * (1.f / 1024.f) - mu * mu;
      float is = rsqrtf(var + 1e-5f);
      #pragma unroll
      for (int j = 0; j < 4; j++) {
        int n = tid + j * 256;
        P.ns[g * 1024 + n] = (val[j] - mu) * is * P.syn_g[n] + P.syn_bn[n];
      }
    } else if (g < 128) {
      if (t > 0) op_body(g - 64, t - 1, P, smem, shred);
    }
    gsync(P.bar, epoch);

    // ---- phase C: NLM, 2 n per block ----
    {
      float* At = smem;              // 32*68
      float* w1s = smem + 2176;      // 8192
      float* b1s = smem + 10368;     // 256
      float* w2s = smem + 10624;     // 128
      int tb = tid >> 5, tjj = tid & 31;
      for (int q = 0; q < 2; q++) {
        int n = g * 2 + q;
        const float4* tw4 = (const float4*)(P.trace + n * TRN + (t + 1) * 64);
        #pragma unroll
        for (int r = 0; r < 2; r++) {
          int idx = r * 256 + tid;
          if (idx < 496) {
            float4 f4 = tw4[idx];
            int fo = idx * 4, m = fo >> 6, bb = fo & 63;
            *(float4*)(At + m * 68 + bb) = f4;
          }
        }
        if (tid < 64) {
          float v = P.ns[tid * 1024 + n];
          At[31 * 68 + tid] = v;
          P.trace[n * TRN + (32 + t) * 64 + tid] = v;
        }
        const float4* w1n = (const float4*)(P.nlm_w1 + n * 8192);
        float4* w1s4 = (float4*)w1s;
        #pragma unroll
        for (int r = 0; r < 8; r++) w1s4[r * 256 + tid] = w1n[r * 256 + tid];
        b1s[tid] = P.nlm_b1[n * 256 + tid];
        if (tid < 128) w2s[tid] = P.nlm_w2[n * 128 + tid];
        __syncthreads();

        float h[8][8];
        #pragma unroll
        for (int jj = 0; jj < 8; jj++) {
          float bv = b1s[tjj + 32 * jj];
          #pragma unroll
          for (int i = 0; i < 8; i++) h[i][jj] = bv;
        }
        for (int m = 0; m < 32; m++) {
          float4 a0 = *(const float4*)(At + m * 68 + tb * 8);
          float4 a1 = *(const float4*)(At + m * 68 + tb * 8 + 4);
          float a[8] = {a0.x, a0.y, a0.z, a0.w, a1.x, a1.y, a1.z, a1.w};
          float wv[8];
          #pragma unroll
          for (int jj = 0; jj < 8; jj++) wv[jj] = w1s[m * 256 + tjj + 32 * jj];
          #pragma unroll
          for (int i = 0; i < 8; i++)
            #pragma unroll
            for (int jj = 0; jj < 8; jj++) h[i][jj] += a[i] * wv[jj];
        }
        float b2n = P.nlm_b2[n];
        #pragma unroll
        for (int i = 0; i < 8; i++) {
          float p = 0.f;
          #pragma unroll
          for (int jj = 0; jj < 4; jj++) {
            float hh = h[i][jj] * sigmoidf(h[i][jj + 4]);
            p += hh * w2s[tjj + 32 * jj];
          }
          #pragma unroll
          for (int off = 16; off > 0; off >>= 1) p += __shfl_xor(p, off, 64);
          if (tjj == 0) P.act[(tb * 8 + i) * 1024 + n] = p + b2n;
        }
        __syncthreads();
      }
    }
    gsync(P.bar, epoch);
  }

  // ---- tail: op head for t=24 ----
  if (g < 64) op_body(g, 24, P, smem, shred);
}

extern "C" void kernel_launch(void* const* d_in, const int* in_sizes, int n_in,
                              void* d_out, int out_size, void* d_ws, size_t ws_size,
                              hipStream_t stream) {
  Params P;
  P.x       = (const float*)d_in[0];
  P.sas     = (const float*)d_in[1];
  P.st      = (const float*)d_in[2];
  P.ie_w1   = (const float*)d_in[3];
  P.ie_b1   = (const float*)d_in[4];
  P.ie_g1   = (const float*)d_in[5];
  P.ie_bn1  = (const float*)d_in[6];
  P.ie_w2   = (const float*)d_in[7];
  P.ie_b2   = (const float*)d_in[8];
  P.ie_g2   = (const float*)d_in[9];
  P.ie_bn2  = (const float*)d_in[10];
  P.ie_w3   = (const float*)d_in[11];
  P.ie_b3   = (const float*)d_in[12];
  P.kv_w    = (const float*)d_in[13];
  P.kv_b    = (const float*)d_in[14];
  P.kv_g    = (const float*)d_in[15];
  P.kv_bn   = (const float*)d_in[16];
  P.ip_w    = (const float*)d_in[19];
  P.ip_b    = (const float*)d_in[20];
  P.op_w    = (const float*)d_in[21];
  P.op_b    = (const float*)d_in[22];
  P.syn_w   = (const float*)d_in[23];
  P.syn_b   = (const float*)d_in[24];
  P.syn_g   = (const float*)d_in[25];
  P.syn_bn  = (const float*)d_in[26];
  P.nlm_w1  = (const float*)d_in[27];
  P.nlm_b1  = (const float*)d_in[28];
  P.nlm_w2  = (const float*)d_in[29];
  P.nlm_b2  = (const float*)d_in[30];
  P.decay_o = (const float*)d_in[32];
  P.op_w1   = (const float*)d_in[33];
  P.op_b1   = (const float*)d_in[34];
  P.op_g1   = (const float*)d_in[35];
  P.op_bn1  = (const float*)d_in[36];
  P.op_w2   = (const float*)d_in[37];
  P.op_b2   = (const float*)d_in[38];
  P.op_g2   = (const float*)d_in[39];
  P.op_bn2  = (const float*)d_in[40];
  P.op_w3   = (const float*)d_in[41];
  P.op_b3   = (const float*)d_in[42];
  P.il      = (const int*)d_in[43];
  P.ir      = (const int*)d_in[44];
  P.out     = (float*)d_out;

  float* ws = (float*)d_ws;
  P.bar   = (unsigned*)ws;         // 8 counters x 32 u32 apart (1KB)
  P.attn  = ws + 256;              // 32768
  P.act   = P.attn + 32768;        // 65536
  P.aO    = P.act + 65536;         // 32768
  P.bO    = P.aO + 32768;          // 32768
  P.ns    = P.bO + 32768;          // 65536
  P.w1t   = P.ns + 65536;          // 131072
  P.w2t   = P.w1t + 131072;        // 16384
  P.part  = P.w2t + 16384;         // 16*64*2048 = 2097152
  P.trace = P.part + 2097152;      // 1024*3648 = 3735552
  P.eb1   = P.trace + 3735552;     // 8192
  P.eb2   = P.eb1 + 8192;          // 4096
  P.enc   = P.eb2 + 4096;          // 32768
  P.kv    = P.enc + 32768;         // 32768
  P.vv    = P.kv + 32768;          // 32768

  hipMemsetAsync(P.bar, 0, 1024, stream);
  k_main<<<NBLK, 256, 0, stream>>>(P);
}

// Round 7
// 5576.402 us; speedup vs baseline: 1.5387x; 1.2933x over previous
//
#include <hip/hip_runtime.h>
#include <math.h>

// Dims: B=64, N=1024, M=32, T=25, R=512, SO=512, OD=10
#define TRW 57
#define TRN (TRW * 64)   // floats per n in trace, layout [n][col][b]
#define NBLK 512

struct Params {
  const float *x, *sas, *st;
  const float *ie_w1, *ie_b1, *ie_g1, *ie_bn1;
  const float *ie_w2, *ie_b2, *ie_g2, *ie_bn2;
  const float *ie_w3, *ie_b3;
  const float *kv_w, *kv_b, *kv_g, *kv_bn;
  const float *ip_w, *ip_b, *op_w, *op_b;
  const float *syn_w, *syn_b, *syn_g, *syn_bn;
  const float *nlm_w1, *nlm_b1, *nlm_w2, *nlm_b2;
  const float *decay_o;
  const float *op_w1, *op_b1, *op_g1, *op_bn1;
  const float *op_w2, *op_b2, *op_g2, *op_bn2;
  const float *op_w3, *op_b3;
  const int *il, *ir;
  float *out;
  unsigned *bar;
  float *attn, *act, *aO, *bO, *ns, *w1t, *w2t, *part, *trace;
  float *eb1, *eb2, *enc, *kv, *vv;
};

// Coherent (agent-scope, L1/L2-bypassing) access for cross-block data.
// These never create dirty or stale L2 lines -> no cache fences needed.
__device__ __forceinline__ float cload(const float* p) {
  return __hip_atomic_load(p, __ATOMIC_RELAXED, __HIP_MEMORY_SCOPE_AGENT);
}
__device__ __forceinline__ void cstore(float* p, float v) {
  __hip_atomic_store(p, v, __ATOMIC_RELAXED, __HIP_MEMORY_SCOPE_AGENT);
}

// Fence-free grid barrier. All NBLK blocks co-resident (LDS 45KB -> 3/CU,
// launch_bounds(256,2) -> 2/CU by VGPR; grid = 2*256 exactly).
// __syncthreads drains each wave's stores (s_waitcnt before s_barrier);
// cross-block data is coherent-by-construction, so NO threadfence.
__device__ __forceinline__ void gsync(unsigned* bar, unsigned& epoch) {
  __syncthreads();
  if (threadIdx.x == 0) {
    epoch += 1;
    unsigned target = epoch * (NBLK / 8);
    __builtin_amdgcn_s_waitcnt(0);   // belt & suspenders: drain wave0 stores
    __hip_atomic_fetch_add(&bar[(blockIdx.x & 7) * 32], 1u,
                           __ATOMIC_RELAXED, __HIP_MEMORY_SCOPE_AGENT);
    for (;;) {
      unsigned ok = 0;
      #pragma unroll
      for (int i = 0; i < 8; i++)
        ok += (__hip_atomic_load(&bar[i * 32], __ATOMIC_RELAXED,
                                 __HIP_MEMORY_SCOPE_AGENT) >= target) ? 1u : 0u;
      if (ok == 8) break;
      __builtin_amdgcn_s_sleep(1);
    }
  }
  __syncthreads();
}

__device__ __forceinline__ float wave_sum(float v) {
  #pragma unroll
  for (int off = 32; off; off >>= 1) v += __shfl_xor(v, off, 64);
  return v;
}

__device__ __forceinline__ float2 block_sum2_256(float a, float b, float2* sh) {
  a = wave_sum(a); b = wave_sum(b);
  int w = threadIdx.x >> 6, l = threadIdx.x & 63;
  if (l == 0) sh[w] = make_float2(a, b);
  __syncthreads();
  float2 r = make_float2(0.f, 0.f);
  #pragma unroll
  for (int i = 0; i < 4; i++) { r.x += sh[i].x; r.y += sh[i].y; }
  __syncthreads();
  return r;
}

__device__ __forceinline__ float sigmoidf(float x) {
  return 1.f / (1.f + expf(-x));
}

// output-parallel GEMV: out[64][O] = A[64][K] @ W[O][K]^T + bias
// A read coherently (cross-block buffer), out written coherently.
__device__ void gemv4(int g, int tid, const float* __restrict__ A,
                      const float* __restrict__ W, const float* __restrict__ bias,
                      float* __restrict__ out, int K, int O, float* aL) {
  int b = g >> 3, w = tid >> 6, l = tid & 63;
  for (int k = tid; k < K; k += 256) aL[k] = cload(&A[b * K + k]);
  __syncthreads();
  int wb = (g & 7) * 4 + w;
  int ngrp = O >> 2;
  for (int gi = wb; gi < ngrp; gi += 32) {
    int o0 = gi * 4;
    float s0 = 0.f, s1 = 0.f, s2 = 0.f, s3 = 0.f;
    for (int ki = l; ki < K; ki += 64) {
      float av = aL[ki];
      s0 = fmaf(av, W[(o0 + 0) * K + ki], s0);
      s1 = fmaf(av, W[(o0 + 1) * K + ki], s1);
      s2 = fmaf(av, W[(o0 + 2) * K + ki], s2);
      s3 = fmaf(av, W[(o0 + 3) * K + ki], s3);
    }
    s0 = wave_sum(s0); s1 = wave_sum(s1); s2 = wave_sum(s2); s3 = wave_sum(s3);
    if (l == 0) {
      cstore(&out[b * O + o0 + 0], s0 + bias[o0 + 0]);
      cstore(&out[b * O + o0 + 1], s1 + bias[o0 + 1]);
      cstore(&out[b * O + o0 + 2], s2 + bias[o0 + 2]);
      cstore(&out[b * O + o0 + 3], s3 + bias[o0 + 3]);
    }
  }
  __syncthreads();
}

// in-place coherent LayerNorm over V values of row g
__device__ void ln_ip(int tid, float* buf, const float* ga, const float* be,
                      int V, bool relu, float2* shred) {
  float x0 = 0.f, x1 = 0.f, v0 = 0.f, v1 = 0.f;
  if (V == 512) {
    x0 = cload(&buf[tid]); x1 = cload(&buf[tid + 256]);
    v0 = x0 + x1; v1 = x0 * x0 + x1 * x1;
  } else if (tid < V) {
    x0 = cload(&buf[tid]); v0 = x0; v1 = x0 * x0;
  }
  float2 s = block_sum2_256(v0, v1, shred);
  float mu = s.x / V, var = s.y / V - mu * mu;
  float is = rsqrtf(var + 1e-5f);
  if (V == 512) {
    float y0 = (x0 - mu) * is * ga[tid] + be[tid];
    float y1 = (x1 - mu) * is * ga[tid + 256] + be[tid + 256];
    cstore(&buf[tid], relu ? fmaxf(y0, 0.f) : y0);
    cstore(&buf[tid + 256], relu ? fmaxf(y1, 0.f) : y1);
  } else if (tid < V) {
    float y = (x0 - mu) * is * ga[tid] + be[tid];
    cstore(&buf[tid], relu ? fmaxf(y, 0.f) : y);
  }
}

// op head for batch row b at step t; always on block 64+b (aO/bO private)
__device__ void op_body(int b, int t, const Params& P, float* sm, float2* shred) {
  float* so = sm;            // 512
  float* p1s = sm + 512;     // 256
  float* qred = sm + 768;    // 256
  float* p2s = sm + 1024;    // 64
  float* preds = sm + 1088;  // 10
  int tid = threadIdx.x;
  #pragma unroll
  for (int r = 0; r < 2; r++) {
    int o = r * 256 + tid;
    float rr = expf(-fminf(fmaxf(P.decay_o[o], 0.f), 15.f));
    float pp = cload(&P.act[b * 1024 + P.il[o]]) * cload(&P.act[b * 1024 + P.ir[o]]);
    float a = rr * P.aO[b * 512 + o] + pp;
    float bbv = rr * P.bO[b * 512 + o] + 1.f;
    P.aO[b * 512 + o] = a;
    P.bO[b * 512 + o] = bbv;
    so[o] = a * rsqrtf(bbv + 1e-8f);
  }
  __syncthreads();
  float p = P.op_b1[tid];
  #pragma unroll 8
  for (int k = 0; k < 512; k++) p += so[k] * P.w1t[k * 256 + tid];
  float2 s = block_sum2_256(p, p * p, shred);
  {
    float mu = s.x * (1.f / 256.f), var = s.y * (1.f / 256.f) - mu * mu;
    p1s[tid] = fmaxf((p - mu) * rsqrtf(var + 1e-5f) * P.op_g1[tid] + P.op_bn1[tid], 0.f);
  }
  __syncthreads();
  {
    int o = tid & 63, tg = tid >> 6;
    float q = 0.f;
    #pragma unroll 4
    for (int j = 0; j < 64; j++) {
      int k = tg * 64 + j;
      q += p1s[k] * P.w2t[k * 64 + o];
    }
    qred[tid] = q;
  }
  __syncthreads();
  if (tid < 64) {
    float p2 = qred[tid] + qred[tid + 64] + qred[tid + 128] + qred[tid + 192] + P.op_b2[tid];
    float sa = wave_sum(p2), sb = wave_sum(p2 * p2);
    float mu = sa * (1.f / 64.f), var = sb * (1.f / 64.f) - mu * mu;
    float y = (p2 - mu) * rsqrtf(var + 1e-5f) * P.op_g2[tid] + P.op_bn2[tid];
    p2s[tid] = fmaxf(y, 0.f);
  }
  __syncthreads();
  if (tid < 160) {
    int o = tid >> 4, j = tid & 15;
    const float* w3r = P.op_w3 + o * 64 + j * 4;
    const float* pp2 = p2s + j * 4;
    float sv = w3r[0] * pp2[0] + w3r[1] * pp2[1] + w3r[2] * pp2[2] + w3r[3] * pp2[3];
    #pragma unroll
    for (int off = 8; off; off >>= 1) sv += __shfl_xor(sv, off, 64);
    if (j == 0) {
      float pr = sv + P.op_b3[o];
      preds[o] = pr;
      P.out[b * 250 + o * 25 + t] = pr;
    }
  }
  __syncthreads();
  if (tid == 0) {
    float mx = preds[0];
    #pragma unroll
    for (int k = 1; k < 10; k++) mx = fmaxf(mx, preds[k]);
    float sum = 0.f, e[10];
    #pragma unroll
    for (int k = 0; k < 10; k++) { e[k] = expf(preds[k] - mx); sum += e[k]; }
    float ent = 0.f;
    #pragma unroll
    for (int k = 0; k < 10; k++) {
      float pr = e[k] / sum;
      ent -= pr * logf(pr + 1e-10f);
    }
    ent *= (1.f / 2.302585093f);
    P.out[16000 + b * 50 + t] = ent;
    P.out[16000 + b * 50 + 25 + t] = 1.f - ent;
  }
  __syncthreads();
}

__global__ __launch_bounds__(256, 2) void k_main(Params P) {
  int g = blockIdx.x, tid = threadIdx.x;
  unsigned epoch = 0;
  __shared__ float smem[11264];     // 44 KB phase-shared scratch
  __shared__ float2 shred[16];

  // ================= phase 0: setup =================
  {
    // trace init: block g owns n = 2g, 2g+1 (private forever after)
    #pragma unroll
    for (int q = 0; q < 2; q++) {
      int n = g * 2 + q;
      #pragma unroll
      for (int r = 0; r < 8; r++) {
        int idx = r * 256 + tid;       // = j*64 + b, j<32
        P.trace[n * TRN + idx] = P.st[n * 32 + (idx >> 6)];
      }
    }
    if (tid < 128) {                   // act: coherent (cross-block buffer)
      int i = g * 128 + tid;
      cstore(&P.act[i], P.sas[i & 1023]);
    }
    if (g >= 64 && g < 128) {          // aO/bO: private to op owner block 64+b
      int b = g - 64;
      #pragma unroll
      for (int r = 0; r < 2; r++) {
        int o = r * 256 + tid;
        P.aO[b * 512 + o] = P.sas[P.il[o]] * P.sas[P.ir[o]];
        P.bO[b * 512 + o] = 1.f;
      }
    }
    { int i = g * 256 + tid; int o = i & 255, k = i >> 8;   // w1t write-once
      cstore(&P.w1t[i], P.op_w1[o * 512 + k]); }
    if (g < 64) { int i = g * 256 + tid; int o = i & 63, k = i >> 6;
      cstore(&P.w2t[i], P.op_w2[o * 256 + k]); }
  }
  gsync(P.bar, epoch);

  // ================= encoder =================
  gemv4(g, tid, P.x, P.ie_w1, P.ie_b1, P.eb1, 784, 128, smem);
  gsync(P.bar, epoch);
  if (g < 64) ln_ip(tid, P.eb1 + g * 128, P.ie_g1, P.ie_bn1, 128, true, shred);
  gsync(P.bar, epoch);
  gemv4(g, tid, P.eb1, P.ie_w2, P.ie_b2, P.eb2, 128, 64, smem);
  gsync(P.bar, epoch);
  if (g < 64) ln_ip(tid, P.eb2 + g * 64, P.ie_g2, P.ie_bn2, 64, true, shred);
  gsync(P.bar, epoch);
  gemv4(g, tid, P.eb2, P.ie_w3, P.ie_b3, P.enc, 64, 512, smem);
  gsync(P.bar, epoch);
  gemv4(g, tid, P.enc, P.kv_w, P.kv_b, P.kv, 512, 512, smem);
  gsync(P.bar, epoch);
  if (g < 64) ln_ip(tid, P.kv + g * 512, P.kv_g, P.kv_bn, 512, false, shred);
  gsync(P.bar, epoch);
  gemv4(g, tid, P.kv, P.ip_w + 1024 * 512, P.ip_b + 1024, P.vv, 512, 512, smem);
  gsync(P.bar, epoch);
  gemv4(g, tid, P.vv, P.op_w, P.op_b, P.attn, 512, 512, smem);
  gsync(P.bar, epoch);

  // ================= 25 steps =================
  for (int t = 0; t < 25; t++) {
    // ---- phase A: syn GEMM, 512 tiles (32 ct x 16 kc), K-chunk 96 ----
    {
      float* pre_t = smem;           // 32*68
      float* w_lds = smem + 2176;    // 32*68
      int ct = g & 31, kc = g >> 5;
      int tb = tid >> 4, tc = tid & 15;
      int b0 = tb * 4, c0 = tc * 4;
      float acc[4][4];
      #pragma unroll
      for (int i = 0; i < 4; i++)
        #pragma unroll
        for (int j = 0; j < 4; j++) acc[i][j] = 0.f;
      for (int kt = 0; kt < 96; kt += 32) {
        int k0 = kc * 96 + kt;
        #pragma unroll
        for (int r = 0; r < 8; r++) {
          int idx = r * 256 + tid;
          int kk = idx & 31, bb = idx >> 5;
          int kg = k0 + kk;
          // attn: write-once -> cached; act: mutable cross-block -> coherent
          float pv = (kg < 512) ? P.attn[bb * 512 + kg]
                                : cload(&P.act[bb * 1024 + (kg - 512)]);
          pre_t[kk * 68 + bb] = pv;
          w_lds[kk * 68 + bb] = P.syn_w[(ct * 64 + bb) * 1536 + kg];
        }
        __syncthreads();
        #pragma unroll 8
        for (int kk = 0; kk < 32; kk++) {
          float4 av = *(const float4*)(pre_t + kk * 68 + b0);
          float4 wv = *(const float4*)(w_lds + kk * 68 + c0);
          float a[4] = {av.x, av.y, av.z, av.w};
          float w[4] = {wv.x, wv.y, wv.z, wv.w};
          #pragma unroll
          for (int i = 0; i < 4; i++)
            #pragma unroll
            for (int j = 0; j < 4; j++) acc[i][j] += a[i] * w[j];
        }
        __syncthreads();
      }
      float* pb = P.part + kc * 131072 + ct * 64 + c0;
      #pragma unroll
      for (int i = 0; i < 4; i++)
        #pragma unroll
        for (int j = 0; j < 4; j++)
          cstore(&pb[(b0 + i) * 2048 + j], acc[i][j]);
    }
    gsync(P.bar, epoch);

    // ---- phase B: syn_ln (blocks 0..63) + op(t-1) (blocks 64..127) ----
    if (g < 64) {
      float val[4];
      float s0 = 0.f, s1 = 0.f;
      #pragma unroll
      for (int j = 0; j < 4; j++) {
        int n = tid + j * 256;
        float a = P.syn_b[n], gg = P.syn_b[n + 1024];
        #pragma unroll
        for (int kc = 0; kc < 16; kc++) {
          const float* pb = P.part + kc * 131072 + g * 2048;
          a += cload(&pb[n]);
          gg += cload(&pb[n + 1024]);
        }
        float v = a * sigmoidf(gg);
        val[j] = v; s0 += v; s1 += v * v;
      }
      float2 s = block_sum2_256(s0, s1, shred);
      float mu = s.x * (1.f / 1024.f), var = s.y * (1.f / 1024.f) - mu * mu;
      float is = rsqrtf(var + 1e-5f);
      #pragma unroll
      for (int j = 0; j < 4; j++) {
        int n = tid + j * 256;
        cstore(&P.ns[g * 1024 + n], (val[j] - mu) * is * P.syn_g[n] + P.syn_bn[n]);
      }
    } else if (g < 128) {
      if (t > 0) op_body(g - 64, t - 1, P, smem, shred);
    }
    gsync(P.bar, epoch);

    // ---- phase C: NLM, 2 n per block (trace rows private to this block) ----
    {
      float* At = smem;              // 32*68
      float* w1s = smem + 2176;      // 8192
      float* b1s = smem + 10368;     // 256
      float* w2s = smem + 10624;     // 128
      int tb = tid >> 5, tjj = tid & 31;
      for (int q = 0; q < 2; q++) {
        int n = g * 2 + q;
        const float4* tw4 = (const float4*)(P.trace + n * TRN + (t + 1) * 64);
        #pragma unroll
        for (int r = 0; r < 2; r++) {
          int idx = r * 256 + tid;
          if (idx < 496) {
            float4 f4 = tw4[idx];
            int fo = idx * 4, m = fo >> 6, bb = fo & 63;
            *(float4*)(At + m * 68 + bb) = f4;
          }
        }
        if (tid < 64) {
          float v = cload(&P.ns[tid * 1024 + n]);
          At[31 * 68 + tid] = v;
          P.trace[n * TRN + (32 + t) * 64 + tid] = v;   // private, cached
        }
        const float4* w1n = (const float4*)(P.nlm_w1 + n * 8192);
        float4* w1s4 = (float4*)w1s;
        #pragma unroll
        for (int r = 0; r < 8; r++) w1s4[r * 256 + tid] = w1n[r * 256 + tid];
        b1s[tid] = P.nlm_b1[n * 256 + tid];
        if (tid < 128) w2s[tid] = P.nlm_w2[n * 128 + tid];
        __syncthreads();

        float h[8][8];
        #pragma unroll
        for (int jj = 0; jj < 8; jj++) {
          float bv = b1s[tjj + 32 * jj];
          #pragma unroll
          for (int i = 0; i < 8; i++) h[i][jj] = bv;
        }
        for (int m = 0; m < 32; m++) {
          float4 a0 = *(const float4*)(At + m * 68 + tb * 8);
          float4 a1 = *(const float4*)(At + m * 68 + tb * 8 + 4);
          float a[8] = {a0.x, a0.y, a0.z, a0.w, a1.x, a1.y, a1.z, a1.w};
          float wv[8];
          #pragma unroll
          for (int jj = 0; jj < 8; jj++) wv[jj] = w1s[m * 256 + tjj + 32 * jj];
          #pragma unroll
          for (int i = 0; i < 8; i++)
            #pragma unroll
            for (int jj = 0; jj < 8; jj++) h[i][jj] += a[i] * wv[jj];
        }
        float b2n = P.nlm_b2[n];
        #pragma unroll
        for (int i = 0; i < 8; i++) {
          float p = 0.f;
          #pragma unroll
          for (int jj = 0; jj < 4; jj++) {
            float hh = h[i][jj] * sigmoidf(h[i][jj + 4]);
            p += hh * w2s[tjj + 32 * jj];
          }
          #pragma unroll
          for (int off = 16; off > 0; off >>= 1) p += __shfl_xor(p, off, 64);
          if (tjj == 0) cstore(&P.act[(tb * 8 + i) * 1024 + n], p + b2n);
        }
        __syncthreads();
      }
    }
    gsync(P.bar, epoch);
  }

  // ---- tail: op head for t=24 on the owner blocks 64..127 ----
  if (g >= 64 && g < 128) op_body(g - 64, 24, P, smem, shred);
}

extern "C" void kernel_launch(void* const* d_in, const int* in_sizes, int n_in,
                              void* d_out, int out_size, void* d_ws, size_t ws_size,
                              hipStream_t stream) {
  Params P;
  P.x       = (const float*)d_in[0];
  P.sas     = (const float*)d_in[1];
  P.st      = (const float*)d_in[2];
  P.ie_w1   = (const float*)d_in[3];
  P.ie_b1   = (const float*)d_in[4];
  P.ie_g1   = (const float*)d_in[5];
  P.ie_bn1  = (const float*)d_in[6];
  P.ie_w2   = (const float*)d_in[7];
  P.ie_b2   = (const float*)d_in[8];
  P.ie_g2   = (const float*)d_in[9];
  P.ie_bn2  = (const float*)d_in[10];
  P.ie_w3   = (const float*)d_in[11];
  P.ie_b3   = (const float*)d_in[12];
  P.kv_w    = (const float*)d_in[13];
  P.kv_b    = (const float*)d_in[14];
  P.kv_g    = (const float*)d_in[15];
  P.kv_bn   = (const float*)d_in[16];
  P.ip_w    = (const float*)d_in[19];
  P.ip_b    = (const float*)d_in[20];
  P.op_w    = (const float*)d_in[21];
  P.op_b    = (const float*)d_in[22];
  P.syn_w   = (const float*)d_in[23];
  P.syn_b   = (const float*)d_in[24];
  P.syn_g   = (const float*)d_in[25];
  P.syn_bn  = (const float*)d_in[26];
  P.nlm_w1  = (const float*)d_in[27];
  P.nlm_b1  = (const float*)d_in[28];
  P.nlm_w2  = (const float*)d_in[29];
  P.nlm_b2  = (const float*)d_in[30];
  P.decay_o = (const float*)d_in[32];
  P.op_w1   = (const float*)d_in[33];
  P.op_b1   = (const float*)d_in[34];
  P.op_g1   = (const float*)d_in[35];
  P.op_bn1  = (const float*)d_in[36];
  P.op_w2   = (const float*)d_in[37];
  P.op_b2   = (const float*)d_in[38];
  P.op_g2   = (const float*)d_in[39];
  P.op_bn2  = (const float*)d_in[40];
  P.op_w3   = (const float*)d_in[41];
  P.op_b3   = (const float*)d_in[42];
  P.il      = (const int*)d_in[43];
  P.ir      = (const int*)d_in[44];
  P.out     = (float*)d_out;

  float* ws = (float*)d_ws;
  P.bar   = (unsigned*)ws;         // 8 counters x 32 u32 apart (1KB)
  P.attn  = ws + 256;              // 32768
  P.act   = P.attn + 32768;        // 65536
  P.aO    = P.act + 65536;         // 32768
  P.bO    = P.aO + 32768;          // 32768
  P.ns    = P.bO + 32768;          // 65536
  P.w1t   = P.ns + 65536;          // 131072
  P.w2t   = P.w1t + 131072;        // 16384
  P.part  = P.w2t + 16384;         // 16*64*2048 = 2097152
  P.trace = P.part + 2097152;      // 1024*3648 = 3735552
  P.eb1   = P.trace + 3735552;     // 8192
  P.eb2   = P.eb1 + 8192;          // 4096
  P.enc   = P.eb2 + 4096;          // 32768
  P.kv    = P.enc + 32768;         // 32768
  P.vv    = P.kv + 32768;          // 32768

  hipMemsetAsync(P.bar, 0, 1024, stream);
  k_main<<<NBLK, 256, 0, stream>>>(P);
}